// Round 5
// baseline (152.292 us; speedup 1.0000x reference)
//
#include <hip/hip_runtime.h>

// LinearAttention: out[b,n,v] = sum_k q[b,k,n] * ktv[b,k,v],
//                  ktv[b,k,v] = sum_n K[b,n,k] * V[b,n,v]
// B=16, DK=64, N=8192, DV=64, fp32.
//
// R5: async global->LDS DMA (global_load_lds width=16) + fine-grained
// s_waitcnt vmcnt(N) software pipeline (AITER pattern; never drain mid-loop).
//  - p1: wave-private LDS double buffer, 4 rounds x 16 rows, NO barrier in
//    the K-loop. Wait vmcnt(8) keeps next round's 8 DMAs in flight.
//  - p2: ks + q-half0 DMA'd, one __syncthreads (its vmcnt(0) drain readies
//    half0), q-half1 DMA'd after the barrier overlapping half0 compute.
//  - 8x8 register tiles kept (4 ds_read_b128 per 64 wave-FMA).
// Floors: p1 72 MB -> 11.4 us HBM / 10.2 us LDS-issue; p2 64 MB -> 10.2 us.

#define B_   16
#define N_   8192
#define DK_  64
#define DV_  64
#define CH_  32      // chunks; 256 rows/chunk, 64 rows/wave, 4 rounds of 16

// async 16B/lane global->LDS DMA: lds dest = (wave-uniform) l + lane*16
__device__ __forceinline__ void dma16(const void* g, void* l) {
    __builtin_amdgcn_global_load_lds(
        (const __attribute__((address_space(1))) void*)g,
        (__attribute__((address_space(3))) void*)l, 16, 0, 0);
}
// s_waitcnt vmcnt(n) only (gfx9 enc: lgkmcnt=0xF<<8 | expcnt=0x7<<4 | vmcnt)
#define WAITVM(n) __builtin_amdgcn_s_waitcnt(0x0F70 | (n))

// ---------------- Phase 1: partial K^T V ----------------
// grid (32, 16), 256 threads (4 waves). Wave w: rows [w*64, w*64+64) of the
// chunk. Private 16 KB region = double buffer of (4 KB K + 4 KB V).
__global__ __launch_bounds__(256) void p1_partial(
    const float* __restrict__ K, const float* __restrict__ V,
    float* __restrict__ part)
{
    __shared__ float sm[4][4096];   // 64 KB; wave w owns sm[w]

    const int c = blockIdx.x, b = blockIdx.y, t = threadIdx.x;
    const int w = t >> 6, lane = t & 63;
    const int kk = (lane >> 3) * 8;   // 8 k-groups of 8
    const int vv = (lane & 7) * 8;    // 8 v-groups of 8
    float* wsm = sm[w];

    const size_t row0 = (size_t)b * N_ + (size_t)c * 256 + (size_t)w * 64;
    const float4* K4 = (const float4*)(K + row0 * DK_);  // 16 float4/row
    const float4* V4 = (const float4*)(V + row0 * DV_);

    // issue DMA for rounds 0 and 1 (8 instrs each; 1 KB per instr)
    #pragma unroll
    for (int r = 0; r < 2; ++r)
        #pragma unroll
        for (int j = 0; j < 4; ++j) {
            dma16(&K4[r * 256 + j * 64 + lane], &wsm[(r & 1) * 2048 + j * 256]);
            dma16(&V4[r * 256 + j * 64 + lane], &wsm[(r & 1) * 2048 + 1024 + j * 256]);
        }

    float acc[8][8] = {};

    #pragma unroll
    for (int r = 0; r < 4; ++r) {
        if (r < 3) WAITVM(8);        // round r's 8 DMAs done; next 8 in flight
        else       WAITVM(0);
        const float* Kb = &wsm[(r & 1) * 2048];
        const float* Vb = &wsm[(r & 1) * 2048 + 1024];
        #pragma unroll 8
        for (int n = 0; n < 16; ++n) {
            alignas(16) float fk[8], fv[8];
            *(float4*)&fk[0] = *(const float4*)&Kb[n * 64 + kk];
            *(float4*)&fk[4] = *(const float4*)&Kb[n * 64 + kk + 4];
            *(float4*)&fv[0] = *(const float4*)&Vb[n * 64 + vv];
            *(float4*)&fv[4] = *(const float4*)&Vb[n * 64 + vv + 4];
            #pragma unroll
            for (int i = 0; i < 8; ++i)
                #pragma unroll
                for (int j = 0; j < 8; ++j)
                    acc[i][j] += fk[i] * fv[j];
        }
        if (r + 2 < 4) {             // refill the buffer just consumed
            const int rn = r + 2;
            #pragma unroll
            for (int j = 0; j < 4; ++j) {
                dma16(&K4[rn * 256 + j * 64 + lane], &wsm[(rn & 1) * 2048 + j * 256]);
                dma16(&V4[rn * 256 + j * 64 + lane], &wsm[(rn & 1) * 2048 + 1024 + j * 256]);
            }
        }
    }

    // wave partial -> own region; one barrier; cross-wave sum; store
    #pragma unroll
    for (int i = 0; i < 8; ++i) {
        *(float4*)&wsm[(kk + i) * 64 + vv]     = make_float4(acc[i][0], acc[i][1], acc[i][2], acc[i][3]);
        *(float4*)&wsm[(kk + i) * 64 + vv + 4] = make_float4(acc[i][4], acc[i][5], acc[i][6], acc[i][7]);
    }
    __syncthreads();

    float4* P = (float4*)(part + ((size_t)c * B_ + b) * 4096);
    #pragma unroll
    for (int j = 0; j < 4; ++j) {
        const int idx = t + 256 * j;      // < 1024
        const float4 s0 = ((const float4*)sm[0])[idx];
        const float4 s1 = ((const float4*)sm[1])[idx];
        const float4 s2 = ((const float4*)sm[2])[idx];
        const float4 s3 = ((const float4*)sm[3])[idx];
        P[idx] = make_float4(s0.x + s1.x + s2.x + s3.x,
                             s0.y + s1.y + s2.y + s3.y,
                             s0.z + s1.z + s2.z + s3.z,
                             s0.w + s1.w + s2.w + s3.w);
    }
}

// ---------------- Phase 1b: reduce 32 partials -> ktv ----------------
// grid 256 x 256; one float per thread, coalesced, 32-way unrolled.
__global__ __launch_bounds__(256) void p1_reduce(
    const float* __restrict__ part, float* __restrict__ ktv)
{
    const int idx = blockIdx.x * 256 + threadIdx.x;   // [0, 65536)
    float s = 0.f;
    #pragma unroll
    for (int c = 0; c < CH_; ++c)
        s += part[(size_t)c * 65536 + idx];
    ktv[idx] = s;
}

// ---------------- Phase 2: out = q^T ktv ----------------
// grid (32, 16), 256 threads (4 waves). Wave w: 64 n at nb*256+w*64.
// LDS: ks 16 KB shared + 4 x 16 KB wave-private q tiles = 80 KB.
__global__ __launch_bounds__(256) void p2(
    const float* __restrict__ q, const float* __restrict__ ktv,
    float* __restrict__ out)
{
    __shared__ float ks[4096];       // ktv[b], [k][v]
    __shared__ float qs[4][4096];    // wave-private, [k][64 n]

    const int nb = blockIdx.x, b = blockIdx.y, t = threadIdx.x;
    const int w = t >> 6, lane = t & 63;
    const int nl = (lane >> 3) * 8;  // 8 n-groups of 8
    const int vl = (lane & 7) * 8;   // 8 v-groups of 8
    const int n0 = nb * 256 + w * 64;
    float* qsw = qs[w];

    // DMA ks quarter (wave w: 4 KB) + q rows 0..31 (half0, 8 KB)
    const float4* kt4 = (const float4*)(ktv + (size_t)b * 4096);
    #pragma unroll
    for (int j = 0; j < 4; ++j)
        dma16(&kt4[w * 256 + j * 64 + lane], &ks[w * 1024 + j * 256]);

    const float* qb = q + (size_t)b * DK_ * N_ + n0;
    // instr j stages q rows 4j..4j+4 (lane row = 4j + lane/16, col4 = lane%16)
    #pragma unroll
    for (int j = 0; j < 8; ++j)
        dma16(qb + (size_t)(4 * j + (lane >> 4)) * N_ + (lane & 15) * 4,
              &qsw[j * 256]);

    __syncthreads();   // drains vmcnt(0): ks + q half0 visible everywhere

    // q rows 32..63 (half1) fly during half0 compute
    #pragma unroll
    for (int j = 8; j < 16; ++j)
        dma16(qb + (size_t)(4 * j + (lane >> 4)) * N_ + (lane & 15) * 4,
              &qsw[j * 256]);

    float acc[8][8] = {};
    #pragma unroll 8
    for (int k = 0; k < 32; ++k) {
        alignas(16) float fq[8], fv[8];
        *(float4*)&fq[0] = *(const float4*)&qsw[k * 64 + nl];
        *(float4*)&fq[4] = *(const float4*)&qsw[k * 64 + nl + 4];
        *(float4*)&fv[0] = *(const float4*)&ks[k * 64 + vl];
        *(float4*)&fv[4] = *(const float4*)&ks[k * 64 + vl + 4];
        #pragma unroll
        for (int i = 0; i < 8; ++i)
            #pragma unroll
            for (int j = 0; j < 8; ++j)
                acc[i][j] += fq[i] * fv[j];
    }
    WAITVM(0);        // half1 DMAs complete (own wave's region)
    #pragma unroll 8
    for (int k = 32; k < 64; ++k) {
        alignas(16) float fq[8], fv[8];
        *(float4*)&fq[0] = *(const float4*)&qsw[k * 64 + nl];
        *(float4*)&fq[4] = *(const float4*)&qsw[k * 64 + nl + 4];
        *(float4*)&fv[0] = *(const float4*)&ks[k * 64 + vl];
        *(float4*)&fv[4] = *(const float4*)&ks[k * 64 + vl + 4];
        #pragma unroll
        for (int i = 0; i < 8; ++i)
            #pragma unroll
            for (int j = 0; j < 8; ++j)
                acc[i][j] += fq[i] * fv[j];
    }

    float* ob = out + ((size_t)b * N_ + n0 + nl) * DV_ + vl;
    #pragma unroll
    for (int i = 0; i < 8; ++i) {
        *(float4*)&ob[(size_t)i * DV_]     = make_float4(acc[i][0], acc[i][1], acc[i][2], acc[i][3]);
        *(float4*)&ob[(size_t)i * DV_ + 4] = make_float4(acc[i][4], acc[i][5], acc[i][6], acc[i][7]);
    }
}

extern "C" void kernel_launch(void* const* d_in, const int* in_sizes, int n_in,
                              void* d_out, int out_size, void* d_ws, size_t ws_size,
                              hipStream_t stream)
{
    (void)in_sizes; (void)n_in; (void)out_size; (void)ws_size;
    const float* q = (const float*)d_in[0];   // [16, 64, 8192]
    const float* k = (const float*)d_in[1];   // [16, 8192, 64]
    const float* v = (const float*)d_in[2];   // [16, 8192, 64]
    float* out = (float*)d_out;               // [16, 8192, 64]

    // ws: [32][16][4096] partials (8 MB) + [16][4096] ktv (256 KB)
    float* part = (float*)d_ws;
    float* ktv  = part + (size_t)CH_ * B_ * 4096;

    p1_partial<<<dim3(CH_, B_), 256, 0, stream>>>(k, v, part);
    p1_reduce<<<dim3(256), 256, 0, stream>>>(part, ktv);
    p2<<<dim3(32, B_), 256, 0, stream>>>(q, ktv, out);
}